// Round 1
// baseline (613.650 us; speedup 1.0000x reference)
//
#include <hip/hip_runtime.h>
#include <hip/hip_fp16.h>

namespace {
constexpr int C    = 150;
constexpr int HW   = 384 * 512;         // 196608
constexpr int NPIX = 4 * HW;            // 786432
constexpr long CHW = (long)C * HW;
constexpr int TPB  = 512;
constexpr int PPT  = 2;                 // pixels per thread (float2 loads)
constexpr int NBLK = NPIX / (TPB * PPT); // 768
}

// acc[0] = sum_n m_n*(LSE_n - dot_n), acc[1] = sum_n m_n
__global__ __launch_bounds__(TPB) void wcel_main(
    const float* __restrict__ pred,
    const int*   __restrict__ gtb,
    const float* __restrict__ mask,
    const float* __restrict__ weight,
    float* __restrict__ acc)
{
    __shared__ __half wlds[C * C];          // 45 KB: weight matrix in fp16
    __shared__ float rn[TPB / 64], rv[TPB / 64];

    for (int i = threadIdx.x; i < C * C; i += TPB)
        wlds[i] = __float2half(weight[i]);
    __syncthreads();

    float num = 0.f, val = 0.f;
    int p = (blockIdx.x * TPB + threadIdx.x) * PPT;
    if (p < NPIX) {
        int b = p / HW;
        int r = p - b * HW;
        const float* base = pred + (size_t)b * CHW + r;
        float2 m2 = *(const float2*)(mask + p);
        int2   g2 = *(const int2*)(gtb + p);
        const __half* w0 = wlds + g2.x * C;
        const __half* w1 = wlds + g2.y * C;
        float s0 = 0.f, s1 = 0.f, d0 = 0.f, d1 = 0.f;
        #pragma unroll 10
        for (int c = 0; c < C; ++c) {
            float2 x = *(const float2*)(base + (size_t)c * HW);
            d0 = fmaf(__half2float(w0[c]), x.x, d0);
            d1 = fmaf(__half2float(w1[c]), x.y, d1);
            s0 += __expf(x.x);
            s1 += __expf(x.y);
        }
        num = m2.x * (__logf(s0) - d0) + m2.y * (__logf(s1) - d1);
        val = m2.x + m2.y;
    }

    // wave-64 shuffle reduction
    #pragma unroll
    for (int off = 32; off > 0; off >>= 1) {
        num += __shfl_down(num, off);
        val += __shfl_down(val, off);
    }
    int lane = threadIdx.x & 63, wid = threadIdx.x >> 6;
    if (lane == 0) { rn[wid] = num; rv[wid] = val; }
    __syncthreads();
    if (threadIdx.x == 0) {
        float n = 0.f, v = 0.f;
        #pragma unroll
        for (int i = 0; i < TPB / 64; ++i) { n += rn[i]; v += rv[i]; }
        atomicAdd(&acc[0], n);
        atomicAdd(&acc[1], v);
    }
}

__global__ void wcel_final(const float* __restrict__ acc, float* __restrict__ out)
{
    out[0] = acc[0] / acc[1];
}

extern "C" void kernel_launch(void* const* d_in, const int* in_sizes, int n_in,
                              void* d_out, int out_size, void* d_ws, size_t ws_size,
                              hipStream_t stream)
{
    const float* pred   = (const float*)d_in[0];  // [B,C,H,W] fp32
    const int*   gtb    = (const int*)  d_in[1];  // [B,1,H,W] int32
    // d_in[2] = gt (unused by the loss math)
    const float* mask   = (const float*)d_in[3];  // [B,1,H,W] fp32 0/1
    const float* weight = (const float*)d_in[4];  // [C,C] fp32 row-normalized
    float* acc = (float*)d_ws;

    hipMemsetAsync(acc, 0, 2 * sizeof(float), stream);
    wcel_main<<<NBLK, TPB, 0, stream>>>(pred, gtb, mask, weight, acc);
    wcel_final<<<1, 1, 0, stream>>>(acc, (float*)d_out);
}

// Round 2
// 613.204 us; speedup vs baseline: 1.0007x; 1.0007x over previous
//
#include <hip/hip_runtime.h>
#include <hip/hip_fp16.h>

namespace {
constexpr int C    = 150;
constexpr int HW   = 384 * 512;            // 196608
constexpr int NPIX = 4 * HW;               // 786432
constexpr long CHW = (long)C * HW;
constexpr int TPB  = 256;
constexpr int PPT  = 4;                    // pixels per thread (float4 loads)
constexpr int NBLK = NPIX / (TPB * PPT);   // 768
constexpr int WSTR = 154;                  // LDS weight row stride in halves:
                                           // 77 words, gcd(77,32)=1 -> uniform banks,
                                           // rows 4B-aligned for half2 reads
}

// acc[0] = sum_n m_n*(LSE_n - dot_n), acc[1] = sum_n m_n
__global__ __launch_bounds__(TPB) void wcel_main(
    const float* __restrict__ pred,
    const int*   __restrict__ gtb,
    const float* __restrict__ mask,
    const float* __restrict__ weight,
    float* __restrict__ acc)
{
    __shared__ __half wlds[C * WSTR];       // 46.2 KB -> 3 blocks/CU
    __shared__ float rn[TPB / 64], rv[TPB / 64];

    // stage weight fp32->fp16 into LDS with padded row stride
    for (int i = threadIdx.x; i < C * C; i += TPB) {
        int row = i / C;                     // compiler magic-mul
        int col = i - row * C;
        wlds[row * WSTR + col] = __float2half(weight[i]);
    }
    __syncthreads();

    int p = (blockIdx.x * TPB + threadIdx.x) * PPT;
    int b = p / HW;
    int r = p - b * HW;
    const float* base = pred + (size_t)b * CHW + r;

    float4 m4 = *(const float4*)(mask + p);
    int4   g4 = *(const int4*)(gtb + p);
    const __half2* w0 = (const __half2*)(wlds + g4.x * WSTR);
    const __half2* w1 = (const __half2*)(wlds + g4.y * WSTR);
    const __half2* w2 = (const __half2*)(wlds + g4.z * WSTR);
    const __half2* w3 = (const __half2*)(wlds + g4.w * WSTR);

    float s0 = 0.f, s1 = 0.f, s2 = 0.f, s3 = 0.f;
    float d0 = 0.f, d1 = 0.f, d2 = 0.f, d3 = 0.f;

    #pragma unroll 5
    for (int cp = 0; cp < C / 2; ++cp) {
        float4 xa = *(const float4*)(base + (size_t)(2 * cp) * HW);
        float4 xb = *(const float4*)(base + (size_t)(2 * cp + 1) * HW);
        float2 v0 = __half22float2(w0[cp]);   // {w[g0,2cp], w[g0,2cp+1]}
        float2 v1 = __half22float2(w1[cp]);
        float2 v2 = __half22float2(w2[cp]);
        float2 v3 = __half22float2(w3[cp]);

        d0 = fmaf(v0.x, xa.x, d0); d0 = fmaf(v0.y, xb.x, d0);
        d1 = fmaf(v1.x, xa.y, d1); d1 = fmaf(v1.y, xb.y, d1);
        d2 = fmaf(v2.x, xa.z, d2); d2 = fmaf(v2.y, xb.z, d2);
        d3 = fmaf(v3.x, xa.w, d3); d3 = fmaf(v3.y, xb.w, d3);

        s0 += __expf(xa.x); s0 += __expf(xb.x);
        s1 += __expf(xa.y); s1 += __expf(xb.y);
        s2 += __expf(xa.z); s2 += __expf(xb.z);
        s3 += __expf(xa.w); s3 += __expf(xb.w);
    }

    float num = m4.x * (__logf(s0) - d0) + m4.y * (__logf(s1) - d1)
              + m4.z * (__logf(s2) - d2) + m4.w * (__logf(s3) - d3);
    float val = m4.x + m4.y + m4.z + m4.w;

    // wave-64 shuffle reduction
    #pragma unroll
    for (int off = 32; off > 0; off >>= 1) {
        num += __shfl_down(num, off);
        val += __shfl_down(val, off);
    }
    int lane = threadIdx.x & 63, wid = threadIdx.x >> 6;
    if (lane == 0) { rn[wid] = num; rv[wid] = val; }
    __syncthreads();
    if (threadIdx.x == 0) {
        float n = 0.f, v = 0.f;
        #pragma unroll
        for (int i = 0; i < TPB / 64; ++i) { n += rn[i]; v += rv[i]; }
        atomicAdd(&acc[0], n);
        atomicAdd(&acc[1], v);
    }
}

__global__ void wcel_final(const float* __restrict__ acc, float* __restrict__ out)
{
    out[0] = acc[0] / acc[1];
}

extern "C" void kernel_launch(void* const* d_in, const int* in_sizes, int n_in,
                              void* d_out, int out_size, void* d_ws, size_t ws_size,
                              hipStream_t stream)
{
    const float* pred   = (const float*)d_in[0];  // [B,C,H,W] fp32
    const int*   gtb    = (const int*)  d_in[1];  // [B,1,H,W] int32
    // d_in[2] = gt (unused by the loss math)
    const float* mask   = (const float*)d_in[3];  // [B,1,H,W] fp32 0/1
    const float* weight = (const float*)d_in[4];  // [C,C] fp32 row-normalized
    float* acc = (float*)d_ws;

    hipMemsetAsync(acc, 0, 2 * sizeof(float), stream);
    wcel_main<<<NBLK, TPB, 0, stream>>>(pred, gtb, mask, weight, acc);
    wcel_final<<<1, 1, 0, stream>>>(acc, (float*)d_out);
}